// Round 7
// baseline (103.253 us; speedup 1.0000x reference)
//
#include <hip/hip_runtime.h>
#include <hip/hip_bf16.h>
#include <math.h>

#define BS    128
#define NC    1024
#define UNITS 512
#define FEAT  512
#define FOURU 2048
#define KG    4          // k-groups (1024/4 = 256 per group)
#define NT    16         // n-columns per gemm block

typedef short bf16x8 __attribute__((ext_vector_type(8)));
typedef float f32x4  __attribute__((ext_vector_type(4)));

// round-half-up bf16: |err| <= 0.5 ulp (same bound as RNE), 2 VALU ops
__device__ __forceinline__ unsigned short bf_rhu(float f) {
    union { float f; unsigned u; } v; v.f = f;
    return (unsigned short)((v.u + 0x8000u) >> 16);
}
__device__ __forceinline__ unsigned pack2(float a, float b) {
    return (unsigned)bf_rhu(a) | ((unsigned)bf_rhu(b) << 16);
}

// ---- K1: per-row argmax + build A_bf16 = [x | h_states[argmax]] ---------
__global__ __launch_bounds__(256) void argmax_prep_kernel(
    const float* __restrict__ logits, const float* __restrict__ x,
    const float* __restrict__ h_states,
    int* __restrict__ sidx, unsigned* __restrict__ Abf /* uint view, 512/row */)
{
    int b = blockIdx.x;
    int t = threadIdx.x;
    float best = -INFINITY; int bi = 0;
    for (int i = t; i < NC; i += 256) {
        float v = logits[b * NC + i];
        if (v > best) { best = v; bi = i; }
    }
    for (int off = 32; off > 0; off >>= 1) {
        float ov = __shfl_down(best, off);
        int   oi = __shfl_down(bi, off);
        if (ov > best || (ov == best && oi < bi)) { best = ov; bi = oi; }
    }
    __shared__ float sv[4]; __shared__ int si[4]; __shared__ int sbi;
    int wid = t >> 6;
    if ((t & 63) == 0) { sv[wid] = best; si[wid] = bi; }
    __syncthreads();
    if (t == 0) {
        for (int w = 1; w < 4; ++w)
            if (sv[w] > best || (sv[w] == best && si[w] < bi)) { best = sv[w]; bi = si[w]; }
        sidx[b] = bi;
        sbi = bi;
    }
    __syncthreads();
    int st = t & 127;
    const float* srcrow = (t < 128) ? (x + (long)b * FEAT)
                                    : (h_states + (long)sbi * UNITS);
    float4 v = *(const float4*)(srcrow + st * 4);
    unsigned lo = pack2(v.x, v.y), hi = pack2(v.z, v.w);
    unsigned du = (unsigned)b * 512u + (t < 128 ? 0u : 256u) + (unsigned)st * 2u;
    *(uint2*)(Abf + du) = make_uint2(lo, hi);
}

// ---- K2: z_part[kg] = A[:, ks] @ W[ks, :] -- zero LDS, zero barriers ----
// grid (128 nt, 4 kg, 2 mhalf) = 1024 blocks (4/CU). M=64 per block: the two
// m-halves of a (nt,kg) pair read the same 16-KB W slice back-to-back (L2
// reuse), doubling latency-hiding waves at ~zero extra HBM traffic.
// B fragments straight from f32 weights (disjoint across (nt,kg) -> 8 MB
// read exactly once), converted in-register. No staging intermediates.
__global__ __launch_bounds__(256) void gemm_kernel(
    const unsigned short* __restrict__ Abf,   // [128][1024] bf16
    const float* __restrict__ kern, const float* __restrict__ reck,
    float* __restrict__ z_part)               // [KG][128][2048] f32
{
    const int t = threadIdx.x;
    const int wid = t >> 6, lane = t & 63, l15 = lane & 15, quad = lane >> 4;
    const int nt = blockIdx.x, kg = blockIdx.y, mhalf = blockIdx.z;
    const int n  = nt * NT + l15;
    const int mbase = mhalf * 64 + wid * 16;           // this wave's 16 A-rows
    const int k0base = kg * 256;                       // k offset inside A
    const float* W  = (kg < 2) ? kern : reck;
    const int wkbase = (kg & 1) * 256;                 // k offset inside W matrix

    f32x4 acc = {0.f, 0.f, 0.f, 0.f};

    #pragma unroll
    for (int kstep = 0; kstep < 8; ++kstep) {
        int k0  = k0base + kstep * 32 + quad * 8;
        int wk0 = wkbase + kstep * 32 + quad * 8;

        bf16x8 af, wf;
        af = *(const bf16x8*)(Abf + (long)(mbase + l15) * 1024 + k0);
        const float* Wp = W + (long)wk0 * FOURU + n;
        #pragma unroll
        for (int j = 0; j < 8; ++j)
            wf[j] = (short)bf_rhu(Wp[(long)j * FOURU]);

        acc = __builtin_amdgcn_mfma_f32_16x16x32_bf16(af, wf, acc, 0, 0, 0);
    }

    // C/D layout: col = lane&15, row = quad*4 + reg
    float* zp = z_part + (long)kg * BS * FOURU;
    #pragma unroll
    for (int r = 0; r < 4; ++r) {
        int m = mbase + quad * 4 + r;
        zp[(long)m * FOURU + n] = acc[r];
    }
}

// ---- K3: fused LSTM + diff_scatter (KG=4) -------------------------------
__global__ __launch_bounds__(256) void scatter_lstm_kernel(
    const float* __restrict__ z_part, const float* __restrict__ bias,
    const float* __restrict__ h_states, const float* __restrict__ c_states,
    const int* __restrict__ sidx,
    float* __restrict__ h_out, float* __restrict__ out_h, float* __restrict__ out_c)
{
    __shared__ int s[BS];
    int t = threadIdx.x;
    if (t < BS) s[t] = sidx[t];
    __syncthreads();
    int j = blockIdx.x >> 1;
    int u = (blockIdx.x & 1) * 256 + t;

    float ah = h_states[(long)j * UNITS + u];
    float ac = c_states[(long)j * UNITS + u];   // == c0 for any matching b

    float mh = -INFINITY, mc = -INFINITY;
    int count = 0;
    float bi_ = bias[u], bf_ = bias[512 + u], bg_ = bias[1024 + u], bo_ = bias[1536 + u];

    for (int b = 0; b < BS; ++b) {
        if (s[b] == j) {                          // block-uniform branch
            ++count;
            float zi = bi_, zf = bf_, zg = bg_, zo = bo_;
            #pragma unroll
            for (int kg = 0; kg < KG; ++kg) {
                const float* zp = z_part + (long)kg * BS * FOURU + (long)b * FOURU;
                zi += zp[u];
                zf += zp[512 + u];
                zg += zp[1024 + u];
                zo += zp[1536 + u];
            }
            float ig = 1.f / (1.f + expf(-zi));
            float fg = 1.f / (1.f + expf(-zf));
            float gg = tanhf(zg);
            float og = 1.f / (1.f + expf(-zo));
            float c  = fg * ac + ig * gg;
            float h  = og * tanhf(c);
            h_out[(long)b * UNITS + u] = h;
            mh = fmaxf(mh, h);
            mc = fmaxf(mc, c);
        }
    }
    // count==BS: old state never appears in the blend; count==0 -> old state
    out_h[(long)j * UNITS + u] = (count == BS) ? mh : fmaxf(ah, mh);
    out_c[(long)j * UNITS + u] = (count == BS) ? mc : fmaxf(ac, mc);
}

extern "C" void kernel_launch(void* const* d_in, const int* in_sizes, int n_in,
                              void* d_out, int out_size, void* d_ws, size_t ws_size,
                              hipStream_t stream)
{
    (void)in_sizes; (void)n_in; (void)out_size; (void)ws_size;
    const float* x      = (const float*)d_in[0];
    const float* logits = (const float*)d_in[1];
    const float* h_st   = (const float*)d_in[2];
    const float* c_st   = (const float*)d_in[3];
    const float* kern   = (const float*)d_in[4];
    const float* reck   = (const float*)d_in[5];
    const float* bias   = (const float*)d_in[6];

    float* out        = (float*)d_out;
    float* out_h_step = out;                          // (128,512)
    float* out_newh   = out + BS * UNITS;             // (1024,512)
    float* out_newc   = out + BS * UNITS + NC * UNITS;

    char*           ws     = (char*)d_ws;
    int*            sidx   = (int*)ws;                    // 512 B
    unsigned*       Abf    = (unsigned*)(ws + 4096);      // 256 KB (uint view)
    float*          z_part = (float*)(ws + (1u << 20));   // 4 MB

    argmax_prep_kernel<<<BS, 256, 0, stream>>>(logits, x, h_st, sidx, Abf);
    gemm_kernel<<<dim3(128, KG, 2), 256, 0, stream>>>(
        (const unsigned short*)Abf, kern, reck, z_part);
    scatter_lstm_kernel<<<NC * UNITS / 256, 256, 0, stream>>>(
        z_part, bias, h_st, c_st, sidx, out_h_step, out_newh, out_newc);
}